// Round 5
// baseline (261.769 us; speedup 1.0000x reference)
//
#include <hip/hip_runtime.h>
#include <math.h>
#include <float.h>

#define NPIX 2304   // 48*48
#define NPAD 2500   // 50*50
#define DDIM 200    // 25 images * 8 channels

// ws layout in floats
#define OFF_QP    0u          // [2][200][2500]
#define OFF_KP    1000000u    // [2][200][2500]
#define OFF_NK    2000000u    // [2][2500]
#define OFF_INVNK 2005000u    // [2][2304]
#define OFF_PVAL  2009608u    // [2][48][2304]  per-(my) partial best
#define OFF_PIDX  2230792u    // int [2][48][2304]
#define OFF_IDX   2451976u    // int [2][2304]
#define OFF_S     2456584u    // [z][2500][2500]  (1 or 2 buffers, ws_size permitting)
#define OFF_SOFF  OFF_S       // int [2][9][2304] — reuses S region (S dead by then)
#define SSTRIDE   6250000L

// ---------------- stage 1: q = W*x1, k = W*x2, zero-padded, d-major ----------------
__global__ __launch_bounds__(256) void k_qk(const float* __restrict__ x1,
                                            const float* __restrict__ x2,
                                            const float* __restrict__ W,
                                            float* __restrict__ qp,
                                            float* __restrict__ kp) {
    __shared__ float Ws[512];
    const int t = threadIdx.x;
    Ws[t] = W[t];
    Ws[t + 256] = W[t + 256];
    __syncthreads();
    const int img = blockIdx.x / 9;      // 0..49  (b*25 + a)
    const int chunk = blockIdx.x % 9;
    const int pix = chunk * 256 + t;     // 0..2303
    const int b = img / 25, a = img % 25;
    const int y = pix / 48, x = pix % 48;

    float q[8], k[8];
#pragma unroll
    for (int o = 0; o < 8; ++o) { q[o] = 0.f; k[o] = 0.f; }

    const float* p1 = x1 + (size_t)b * 64 * 57600 + a * 2304 + pix;
    const float* p2 = x2 + (size_t)b * 64 * 57600 + a * 2304 + pix;
    for (int c = 0; c < 64; ++c) {
        float v1 = p1[c * 57600];
        float v2 = p2[c * 57600];
#pragma unroll
        for (int o = 0; o < 8; ++o) {
            float w = Ws[o * 64 + c];
            q[o] = fmaf(w, v1, q[o]);
            k[o] = fmaf(w, v2, k[o]);
        }
    }
    const int p = (y + 1) * 50 + (x + 1);
    const size_t base = (size_t)b * 500000 + (size_t)(a * 8) * NPAD + p;
#pragma unroll
    for (int o = 0; o < 8; ++o) {
        qp[base + o * NPAD] = q[o];
        kp[base + o * NPAD] = k[o];
    }
}

// ---------------- per-position squared norms of k ----------------
__global__ void k_nk(const float* __restrict__ kp, float* __restrict__ nk) {
    int t = blockIdx.x * 256 + threadIdx.x;  // 0..4999
    if (t >= 2 * NPAD) return;
    int b = t / NPAD, p = t - b * NPAD;
    const float* src = kp + (size_t)b * 500000 + p;
    float s = 0.f;
    for (int d = 0; d < DDIM; ++d) { float v = src[d * NPAD]; s = fmaf(v, v, s); }
    nk[t] = s;
}

__global__ void k_invnk(const float* __restrict__ nk, float* __restrict__ invNk) {
    int t = blockIdx.x * 256 + threadIdx.x;  // 0..4607
    if (t >= 2 * NPIX) return;
    int b = t / NPIX, m = t - b * NPIX;
    int my = m / 48, mx = m % 48;
    const float* nb = nk + b * NPAD;
    float s = 0.f;
#pragma unroll
    for (int i = 0; i < 3; ++i)
#pragma unroll
        for (int j = 0; j < 3; ++j)
            s += nb[(my + i) * 50 + mx + j];
    invNk[t] = 1.0f / fmaxf(sqrtf(s), 1e-12f);
}

// ---- stage 2a: S = A^T B; 128x128 tiles, 8x8 micro-tile, 1-barrier dbuf, batch in z ----
__global__ __launch_bounds__(256, 4) void k_sgemm3(const float* __restrict__ qp,
                                                   const float* __restrict__ kp,
                                                   float* __restrict__ S,
                                                   long sStride, int bofs) {
    __shared__ __align__(16) float As[2][8][128];
    __shared__ __align__(16) float Bs[2][8][128];
    const int t = threadIdx.x;
    const int batch = bofs + blockIdx.z;
    const float* A = qp + (size_t)batch * 500000;
    const float* B = kp + (size_t)batch * 500000;
    float* Sb = S + (size_t)blockIdx.z * sStride;
    const int p0 = blockIdx.y * 128, r0 = blockIdx.x * 128;

    const int lr = t >> 5, lc = t & 31;  // loader: d-row 0..7, lane-col 0..31
    // Loads deliberately unguarded — max overrun +59 floats lands in adjacent
    // defined finite ws regions; those values only feed acc slots whose stores
    // are guarded below.
    const float* aptr = A + (size_t)lr * NPAD + p0 + lc * 4;
    const float* bptr = B + (size_t)lr * NPAD + r0 + lc * 4;

    float4 areg = *(const float4*)aptr;
    float4 breg = *(const float4*)bptr;
    *(float4*)&As[0][lr][lc * 4] = areg;
    *(float4*)&Bs[0][lr][lc * 4] = breg;
    __syncthreads();

    const int tx = t & 15, ty = t >> 4;
    // acc[i][j]: row p0 + (i>>2)*64 + ty*4 + (i&3), col r0 + (j>>2)*64 + tx*4 + (j&3)
    float acc[8][8];
#pragma unroll
    for (int i = 0; i < 8; ++i)
#pragma unroll
        for (int j = 0; j < 8; ++j) acc[i][j] = 0.f;

    for (int it = 0; it < 25; ++it) {
        const int cur = it & 1;
        if (it + 1 < 25) {  // prefetch next K-slice (hidden under the fma burst)
            areg = *(const float4*)(aptr + (size_t)(it + 1) * 8 * NPAD);
            breg = *(const float4*)(bptr + (size_t)(it + 1) * 8 * NPAD);
        }
#pragma unroll
        for (int dd = 0; dd < 8; ++dd) {
            float a[8], b[8];
            *(float4*)&a[0] = *(const float4*)&As[cur][dd][ty * 4];        // broadcast
            *(float4*)&a[4] = *(const float4*)&As[cur][dd][64 + ty * 4];   // broadcast
            *(float4*)&b[0] = *(const float4*)&Bs[cur][dd][tx * 4];        // conflict-free
            *(float4*)&b[4] = *(const float4*)&Bs[cur][dd][64 + tx * 4];   // conflict-free
#pragma unroll
            for (int i = 0; i < 8; ++i)
#pragma unroll
                for (int j = 0; j < 8; ++j)
                    acc[i][j] = fmaf(a[i], b[j], acc[i][j]);
        }
        if (it + 1 < 25) {
            // write next buffer, ONE barrier: prior-iteration readers of buf
            // cur^1 were ordered by the previous barrier.
            *(float4*)&As[cur ^ 1][lr][lc * 4] = areg;
            *(float4*)&Bs[cur ^ 1][lr][lc * 4] = breg;
            __syncthreads();
        }
    }

#pragma unroll
    for (int ih = 0; ih < 2; ++ih) {
#pragma unroll
        for (int ii = 0; ii < 4; ++ii) {
            const int i = ih * 4 + ii;
            const int p = p0 + ih * 64 + ty * 4 + ii;
            if (p < NPAD) {
                float* srow = Sb + (size_t)p * NPAD;
#pragma unroll
                for (int jh = 0; jh < 2; ++jh) {
                    const int c = r0 + jh * 64 + tx * 4;
                    if (c + 4 <= NPAD) {
                        float4 v = { acc[i][jh * 4], acc[i][jh * 4 + 1],
                                     acc[i][jh * 4 + 2], acc[i][jh * 4 + 3] };
                        *(float4*)&srow[c] = v;
                    } else {
#pragma unroll
                        for (int jj = 0; jj < 4; ++jj)
                            if (c + jj < NPAD) srow[c + jj] = acc[i][jh * 4 + jj];
                    }
                }
            }
        }
    }
}

// ---------------- stage 2b: one block per (my, ly, z); box-sum + partial argmax ----
__global__ __launch_bounds__(384) void k_argmax(const float* __restrict__ S,
                                                const float* __restrict__ invNk,
                                                float* __restrict__ pval,
                                                int* __restrict__ pidx,
                                                long sStride, int bofs) {
    __shared__ float band[3][50][50];
    const int t = threadIdx.x;
    const int my = blockIdx.x;     // 0..47
    const int ly = blockIdx.y;     // 0..47
    const int batch = bofs + blockIdx.z;
    const float* Sb = S + (size_t)blockIdx.z * sStride;
    const int lx = t >> 3;         // 0..47
    const int mc = t & 7;          // 0..7

    for (int e = t; e < 7500; e += 384) {
        int i = e / 2500;
        int rem = e - i * 2500;
        int uu = rem / 50;
        int vv = rem - uu * 50;
        band[i][uu][vv] = Sb[(size_t)((ly + i) * 50 + uu) * NPAD + (my + i) * 50 + vv];
    }
    __syncthreads();

    const float* inb = invNk + batch * NPIX;
    float best = -FLT_MAX;
    int bi = 0x7FFFFFFF;

#pragma unroll
    for (int k = 0; k < 6; ++k) {
        int mx = mc + (k << 3);
        float s = 0.f;
#pragma unroll
        for (int i = 0; i < 3; ++i)
#pragma unroll
            for (int j = 0; j < 3; ++j)
                s += band[i][lx + j][mx + j];
        int m = my * 48 + mx;
        float v = s * inb[m];
        if (v > best || (v == best && m < bi)) { best = v; bi = m; }
    }
#pragma unroll
    for (int off = 1; off < 8; off <<= 1) {
        float ov = __shfl_xor(best, off, 64);
        int oi = __shfl_xor(bi, off, 64);
        if (ov > best || (ov == best && oi < bi)) { best = ov; bi = oi; }
    }
    if (mc == 0) {
        int o = (batch * 48 + my) * NPIX + ly * 48 + lx;
        pval[o] = best;
        pidx[o] = bi;
    }
}

__global__ void k_argred(const float* __restrict__ pval, const int* __restrict__ pidx,
                         int* __restrict__ idxout) {
    int t = blockIdx.x * 256 + threadIdx.x;
    if (t >= 2 * NPIX) return;
    int b = t / NPIX, l = t - b * NPIX;
    float best = -FLT_MAX;
    int bi = 0x7FFFFFFF;
    for (int my = 0; my < 48; ++my) {
        int o = (b * 48 + my) * NPIX + l;
        float v = pval[o];
        int i = pidx[o];
        if (v > best || (v == best && i < bi)) { best = v; bi = i; }
    }
    idxout[t] = bi;
}

// ---------------- stage 3a: per-(b,pixel) 9 source offsets (tap-major layout) --------
__global__ void k_soff(const int* __restrict__ idx, int* __restrict__ soff) {
    int t = blockIdx.x * 256 + threadIdx.x;
    if (t >= 2 * NPIX) return;
    int b = t / NPIX, pix = t - b * NPIX;
    int y = pix / 48, x = pix % 48;
#pragma unroll
    for (int i = 0; i < 3; ++i) {
#pragma unroll
        for (int j = 0; j < 3; ++j) {
            int u = i * 3 + j;
            int yq = y + 1 - i, xq = x + 1 - j;
            int so = -1;
            if (yq >= 0 && yq < 48 && xq >= 0 && xq < 48) {
                int m = idx[b * NPIX + yq * 48 + xq];
                int my = m / 48, mx = m % 48;
                int yy = my + i - 1, xx = mx + j - 1;
                if (yy >= 0 && yy < 48 && xx >= 0 && xx < 48) so = yy * 48 + xx;
            }
            soff[(b * 9 + u) * NPIX + pix] = so;
        }
    }
}

// ---------------- stage 3b: gather + fold via LDS-staged plane ----------------
#define CPB 4  // channels per block
__global__ __launch_bounds__(256) void k_out2(const float* __restrict__ x3,
                                              const int* __restrict__ soff,
                                              float* __restrict__ out) {
    __shared__ __align__(16) float plane[NPIX];
    const int t = threadIdx.x;
    const int img = blockIdx.x;          // 0..49 (b*25 + a)
    const int b = img / 25, a = img % 25;
    const int c0 = blockIdx.y * CPB;

    int po[9][9];
#pragma unroll
    for (int u = 0; u < 9; ++u) {
        const int* sb = soff + (b * 9 + u) * NPIX;
#pragma unroll
        for (int k = 0; k < 9; ++k)
            po[k][u] = sb[k * 256 + t];
    }

    const size_t pbase = (size_t)b * 64 * 57600 + (size_t)a * 2304 + (size_t)c0 * 57600;
    const float* gsrc = x3 + pbase;
    float* gdst = out + pbase;

    float4 r0, r1, r2;
    {
        const float4* g = (const float4*)gsrc;
        r0 = g[t]; r1 = g[t + 256];
        if (t < 64) r2 = g[t + 512];
    }
    float4* pl4 = (float4*)plane;
    pl4[t] = r0; pl4[t + 256] = r1;
    if (t < 64) pl4[t + 512] = r2;
    __syncthreads();

    for (int c = 0; c < CPB; ++c) {
        if (c + 1 < CPB) {
            const float4* g = (const float4*)(gsrc + (size_t)(c + 1) * 57600);
            r0 = g[t]; r1 = g[t + 256];
            if (t < 64) r2 = g[t + 512];
        }
        float* dst = gdst + (size_t)c * 57600;
#pragma unroll
        for (int k = 0; k < 9; ++k) {
            float acc = 0.f;
#pragma unroll
            for (int u = 0; u < 9; ++u) {
                int off = po[k][u];
                int ao = off < 0 ? 0 : off;
                float v = plane[ao];
                acc += (off < 0) ? 0.f : v;
            }
            dst[k * 256 + t] = acc;
        }
        __syncthreads();
        if (c + 1 < CPB) {
            pl4[t] = r0; pl4[t + 256] = r1;
            if (t < 64) pl4[t + 512] = r2;
        }
        __syncthreads();
    }
}

extern "C" void kernel_launch(void* const* d_in, const int* in_sizes, int n_in,
                              void* d_out, int out_size, void* d_ws, size_t ws_size,
                              hipStream_t stream) {
    const float* x1 = (const float*)d_in[0];
    const float* x2 = (const float*)d_in[1];
    const float* x3 = (const float*)d_in[2];
    const float* W  = (const float*)d_in[3];
    float* ws = (float*)d_ws;

    float* qp    = ws + OFF_QP;
    float* kp    = ws + OFF_KP;
    float* nk    = ws + OFF_NK;
    float* invNk = ws + OFF_INVNK;
    float* pval  = ws + OFF_PVAL;
    int*   pidx  = (int*)(ws + OFF_PIDX);
    int*   idx   = (int*)(ws + OFF_IDX);
    float* S     = ws + OFF_S;
    int*   soff  = (int*)(ws + OFF_SOFF);   // aliases S; S is dead by k_soff
    float* out   = (float*)d_out;

    const bool bigS = ws_size >= (size_t)(OFF_S + 2u * (unsigned)SSTRIDE) * 4u;

    // zero-pad borders of qp/kp (contiguous 2M floats)
    hipMemsetAsync(qp, 0, 2000000 * sizeof(float), stream);

    k_qk<<<450, 256, 0, stream>>>(x1, x2, W, qp, kp);
    k_nk<<<(2 * NPAD + 255) / 256, 256, 0, stream>>>(kp, nk);
    k_invnk<<<(2 * NPIX + 255) / 256, 256, 0, stream>>>(nk, invNk);

    if (bigS) {
        k_sgemm3<<<dim3(20, 20, 2), 256, 0, stream>>>(qp, kp, S, SSTRIDE, 0);
        k_argmax<<<dim3(48, 48, 2), 384, 0, stream>>>(S, invNk, pval, pidx, SSTRIDE, 0);
    } else {
        for (int b = 0; b < 2; ++b) {
            k_sgemm3<<<dim3(20, 20, 1), 256, 0, stream>>>(qp, kp, S, 0L, b);
            k_argmax<<<dim3(48, 48, 1), 384, 0, stream>>>(S, invNk, pval, pidx, 0L, b);
        }
    }
    k_argred<<<(2 * NPIX + 255) / 256, 256, 0, stream>>>(pval, pidx, idx);
    k_soff<<<(2 * NPIX + 255) / 256, 256, 0, stream>>>(idx, soff);
    k_out2<<<dim3(50, 16), 256, 0, stream>>>(x3, soff, out);
}

// Round 6
// 188.150 us; speedup vs baseline: 1.3913x; 1.3913x over previous
//
#include <hip/hip_runtime.h>
#include <math.h>
#include <float.h>

#define NPIX 2304   // 48*48
#define NPAD 2500   // 50*50
#define DDIM 200    // 25 images * 8 channels

// ws layout in floats
#define OFF_QP    0u          // [2][200][2500]
#define OFF_KP    1000000u    // [2][200][2500]
#define OFF_NK    2000000u    // [2][2500]
#define OFF_INVNK 2005000u    // [2][2304]
#define OFF_PVAL  2009608u    // [2][48][2304]  per-(my) partial best
#define OFF_PIDX  2230792u    // int [2][48][2304]
#define OFF_IDX   2451976u    // int [2][2304]
#define OFF_S     2456584u    // [z][2500][2500]  (1 or 2 buffers, ws_size permitting)
#define OFF_SOFF  OFF_S       // int [2][9][2304] — reuses S region (S dead by then)
#define SSTRIDE   6250000L

// ---------------- stage 1: q = W*x1, k = W*x2, zero-padded, d-major ----------------
__global__ __launch_bounds__(256) void k_qk(const float* __restrict__ x1,
                                            const float* __restrict__ x2,
                                            const float* __restrict__ W,
                                            float* __restrict__ qp,
                                            float* __restrict__ kp) {
    __shared__ float Ws[512];
    const int t = threadIdx.x;
    Ws[t] = W[t];
    Ws[t + 256] = W[t + 256];
    __syncthreads();
    const int img = blockIdx.x / 9;      // 0..49  (b*25 + a)
    const int chunk = blockIdx.x % 9;
    const int pix = chunk * 256 + t;     // 0..2303
    const int b = img / 25, a = img % 25;
    const int y = pix / 48, x = pix % 48;

    float q[8], k[8];
#pragma unroll
    for (int o = 0; o < 8; ++o) { q[o] = 0.f; k[o] = 0.f; }

    const float* p1 = x1 + (size_t)b * 64 * 57600 + a * 2304 + pix;
    const float* p2 = x2 + (size_t)b * 64 * 57600 + a * 2304 + pix;
    for (int c = 0; c < 64; ++c) {
        float v1 = p1[c * 57600];
        float v2 = p2[c * 57600];
#pragma unroll
        for (int o = 0; o < 8; ++o) {
            float w = Ws[o * 64 + c];
            q[o] = fmaf(w, v1, q[o]);
            k[o] = fmaf(w, v2, k[o]);
        }
    }
    const int p = (y + 1) * 50 + (x + 1);
    const size_t base = (size_t)b * 500000 + (size_t)(a * 8) * NPAD + p;
#pragma unroll
    for (int o = 0; o < 8; ++o) {
        qp[base + o * NPAD] = q[o];
        kp[base + o * NPAD] = k[o];
    }
}

// ---------------- per-position squared norms of k ----------------
__global__ void k_nk(const float* __restrict__ kp, float* __restrict__ nk) {
    int t = blockIdx.x * 256 + threadIdx.x;  // 0..4999
    if (t >= 2 * NPAD) return;
    int b = t / NPAD, p = t - b * NPAD;
    const float* src = kp + (size_t)b * 500000 + p;
    float s = 0.f;
    for (int d = 0; d < DDIM; ++d) { float v = src[d * NPAD]; s = fmaf(v, v, s); }
    nk[t] = s;
}

__global__ void k_invnk(const float* __restrict__ nk, float* __restrict__ invNk) {
    int t = blockIdx.x * 256 + threadIdx.x;  // 0..4607
    if (t >= 2 * NPIX) return;
    int b = t / NPIX, m = t - b * NPIX;
    int my = m / 48, mx = m % 48;
    const float* nb = nk + b * NPAD;
    float s = 0.f;
#pragma unroll
    for (int i = 0; i < 3; ++i)
#pragma unroll
        for (int j = 0; j < 3; ++j)
            s += nb[(my + i) * 50 + mx + j];
    invNk[t] = 1.0f / fmaxf(sqrtf(s), 1e-12f);
}

// ---- stage 2a: S = A^T B; 128x128 tiles, 8x8 micro-tile, 1-barrier dbuf, batch in z ----
// launch_bounds(256,2): R5's (256,4) capped VGPRs at 64 -> acc[8][8] spilled to
// scratch (WRITE_SIZE +124MB, FETCH +127MB). 2 waves/EU min lets the allocator
// take ~110-130 VGPRs; HW occupancy follows 512/VGPR anyway.
__global__ __launch_bounds__(256, 2) void k_sgemm3(const float* __restrict__ qp,
                                                   const float* __restrict__ kp,
                                                   float* __restrict__ S,
                                                   long sStride, int bofs) {
    __shared__ __align__(16) float As[2][8][128];
    __shared__ __align__(16) float Bs[2][8][128];
    const int t = threadIdx.x;

    // XCD-aware bijective swizzle: HW round-robins linear block id across 8
    // XCDs; remap so each XCD gets a CONTIGUOUS chunk of work ids (5 p-rows x
    // all r-tiles ~= 2.5 MB working set < 4 MB per-XCD L2). nwg is 800 or 400,
    // both divisible by 8.
    const int nwg = gridDim.x * gridDim.y * gridDim.z;
    const int lin = (blockIdx.z * gridDim.y + blockIdx.y) * gridDim.x + blockIdx.x;
    const int work = (lin & 7) * (nwg >> 3) + (lin >> 3);
    const int z = work / 400;
    const int rem = work - z * 400;
    const int wy = rem / 20, wx = rem - (rem / 20) * 20;

    const int batch = bofs + z;
    const float* A = qp + (size_t)batch * 500000;
    const float* B = kp + (size_t)batch * 500000;
    float* Sb = S + (size_t)z * sStride;
    const int p0 = wy * 128, r0 = wx * 128;

    const int lr = t >> 5, lc = t & 31;  // loader: d-row 0..7, lane-col 0..31
    // Loads deliberately unguarded — max overrun +59 floats lands in adjacent
    // defined finite ws regions; those values only feed acc slots whose stores
    // are guarded below.
    const float* aptr = A + (size_t)lr * NPAD + p0 + lc * 4;
    const float* bptr = B + (size_t)lr * NPAD + r0 + lc * 4;

    float4 areg = *(const float4*)aptr;
    float4 breg = *(const float4*)bptr;
    *(float4*)&As[0][lr][lc * 4] = areg;
    *(float4*)&Bs[0][lr][lc * 4] = breg;
    __syncthreads();

    const int tx = t & 15, ty = t >> 4;
    // acc[i][j]: row p0 + (i>>2)*64 + ty*4 + (i&3), col r0 + (j>>2)*64 + tx*4 + (j&3)
    float acc[8][8];
#pragma unroll
    for (int i = 0; i < 8; ++i)
#pragma unroll
        for (int j = 0; j < 8; ++j) acc[i][j] = 0.f;

    for (int it = 0; it < 25; ++it) {
        const int cur = it & 1;
        if (it + 1 < 25) {  // prefetch next K-slice (hidden under the fma burst)
            areg = *(const float4*)(aptr + (size_t)(it + 1) * 8 * NPAD);
            breg = *(const float4*)(bptr + (size_t)(it + 1) * 8 * NPAD);
        }
#pragma unroll
        for (int dd = 0; dd < 8; ++dd) {
            float a[8], b[8];
            *(float4*)&a[0] = *(const float4*)&As[cur][dd][ty * 4];        // broadcast
            *(float4*)&a[4] = *(const float4*)&As[cur][dd][64 + ty * 4];   // broadcast
            *(float4*)&b[0] = *(const float4*)&Bs[cur][dd][tx * 4];        // conflict-free
            *(float4*)&b[4] = *(const float4*)&Bs[cur][dd][64 + tx * 4];   // conflict-free
#pragma unroll
            for (int i = 0; i < 8; ++i)
#pragma unroll
                for (int j = 0; j < 8; ++j)
                    acc[i][j] = fmaf(a[i], b[j], acc[i][j]);
        }
        if (it + 1 < 25) {
            // write next buffer, ONE barrier: prior-iteration readers of buf
            // cur^1 were ordered by the previous barrier.
            *(float4*)&As[cur ^ 1][lr][lc * 4] = areg;
            *(float4*)&Bs[cur ^ 1][lr][lc * 4] = breg;
            __syncthreads();
        }
    }

#pragma unroll
    for (int ih = 0; ih < 2; ++ih) {
#pragma unroll
        for (int ii = 0; ii < 4; ++ii) {
            const int i = ih * 4 + ii;
            const int p = p0 + ih * 64 + ty * 4 + ii;
            if (p < NPAD) {
                float* srow = Sb + (size_t)p * NPAD;
#pragma unroll
                for (int jh = 0; jh < 2; ++jh) {
                    const int c = r0 + jh * 64 + tx * 4;
                    if (c + 4 <= NPAD) {
                        float4 v = { acc[i][jh * 4], acc[i][jh * 4 + 1],
                                     acc[i][jh * 4 + 2], acc[i][jh * 4 + 3] };
                        *(float4*)&srow[c] = v;
                    } else {
#pragma unroll
                        for (int jj = 0; jj < 4; ++jj)
                            if (c + jj < NPAD) srow[c + jj] = acc[i][jh * 4 + jj];
                    }
                }
            }
        }
    }
}

// ---------------- stage 2b: one block per (my, ly, z); box-sum + partial argmax ----
__global__ __launch_bounds__(384) void k_argmax(const float* __restrict__ S,
                                                const float* __restrict__ invNk,
                                                float* __restrict__ pval,
                                                int* __restrict__ pidx,
                                                long sStride, int bofs) {
    __shared__ float band[3][50][50];
    const int t = threadIdx.x;
    const int my = blockIdx.x;     // 0..47
    const int ly = blockIdx.y;     // 0..47
    const int batch = bofs + blockIdx.z;
    const float* Sb = S + (size_t)blockIdx.z * sStride;
    const int lx = t >> 3;         // 0..47
    const int mc = t & 7;          // 0..7

    for (int e = t; e < 7500; e += 384) {
        int i = e / 2500;
        int rem = e - i * 2500;
        int uu = rem / 50;
        int vv = rem - uu * 50;
        band[i][uu][vv] = Sb[(size_t)((ly + i) * 50 + uu) * NPAD + (my + i) * 50 + vv];
    }
    __syncthreads();

    const float* inb = invNk + batch * NPIX;
    float best = -FLT_MAX;
    int bi = 0x7FFFFFFF;

#pragma unroll
    for (int k = 0; k < 6; ++k) {
        int mx = mc + (k << 3);
        float s = 0.f;
#pragma unroll
        for (int i = 0; i < 3; ++i)
#pragma unroll
            for (int j = 0; j < 3; ++j)
                s += band[i][lx + j][mx + j];
        int m = my * 48 + mx;
        float v = s * inb[m];
        if (v > best || (v == best && m < bi)) { best = v; bi = m; }
    }
#pragma unroll
    for (int off = 1; off < 8; off <<= 1) {
        float ov = __shfl_xor(best, off, 64);
        int oi = __shfl_xor(bi, off, 64);
        if (ov > best || (ov == best && oi < bi)) { best = ov; bi = oi; }
    }
    if (mc == 0) {
        int o = (batch * 48 + my) * NPIX + ly * 48 + lx;
        pval[o] = best;
        pidx[o] = bi;
    }
}

__global__ void k_argred(const float* __restrict__ pval, const int* __restrict__ pidx,
                         int* __restrict__ idxout) {
    int t = blockIdx.x * 256 + threadIdx.x;
    if (t >= 2 * NPIX) return;
    int b = t / NPIX, l = t - b * NPIX;
    float best = -FLT_MAX;
    int bi = 0x7FFFFFFF;
    for (int my = 0; my < 48; ++my) {
        int o = (b * 48 + my) * NPIX + l;
        float v = pval[o];
        int i = pidx[o];
        if (v > best || (v == best && i < bi)) { best = v; bi = i; }
    }
    idxout[t] = bi;
}

// ---------------- stage 3a: per-(b,pixel) 9 source offsets (tap-major layout) --------
__global__ void k_soff(const int* __restrict__ idx, int* __restrict__ soff) {
    int t = blockIdx.x * 256 + threadIdx.x;
    if (t >= 2 * NPIX) return;
    int b = t / NPIX, pix = t - b * NPIX;
    int y = pix / 48, x = pix % 48;
#pragma unroll
    for (int i = 0; i < 3; ++i) {
#pragma unroll
        for (int j = 0; j < 3; ++j) {
            int u = i * 3 + j;
            int yq = y + 1 - i, xq = x + 1 - j;
            int so = -1;
            if (yq >= 0 && yq < 48 && xq >= 0 && xq < 48) {
                int m = idx[b * NPIX + yq * 48 + xq];
                int my = m / 48, mx = m % 48;
                int yy = my + i - 1, xx = mx + j - 1;
                if (yy >= 0 && yy < 48 && xx >= 0 && xx < 48) so = yy * 48 + xx;
            }
            soff[(b * 9 + u) * NPIX + pix] = so;
        }
    }
}

// ---------------- stage 3b: gather + fold via LDS-staged plane ----------------
#define CPB 4  // channels per block
__global__ __launch_bounds__(256) void k_out2(const float* __restrict__ x3,
                                              const int* __restrict__ soff,
                                              float* __restrict__ out) {
    __shared__ __align__(16) float plane[NPIX];
    const int t = threadIdx.x;
    const int img = blockIdx.x;          // 0..49 (b*25 + a)
    const int b = img / 25, a = img % 25;
    const int c0 = blockIdx.y * CPB;

    int po[9][9];
#pragma unroll
    for (int u = 0; u < 9; ++u) {
        const int* sb = soff + (b * 9 + u) * NPIX;
#pragma unroll
        for (int k = 0; k < 9; ++k)
            po[k][u] = sb[k * 256 + t];
    }

    const size_t pbase = (size_t)b * 64 * 57600 + (size_t)a * 2304 + (size_t)c0 * 57600;
    const float* gsrc = x3 + pbase;
    float* gdst = out + pbase;

    float4 r0, r1, r2;
    {
        const float4* g = (const float4*)gsrc;
        r0 = g[t]; r1 = g[t + 256];
        if (t < 64) r2 = g[t + 512];
    }
    float4* pl4 = (float4*)plane;
    pl4[t] = r0; pl4[t + 256] = r1;
    if (t < 64) pl4[t + 512] = r2;
    __syncthreads();

    for (int c = 0; c < CPB; ++c) {
        if (c + 1 < CPB) {
            const float4* g = (const float4*)(gsrc + (size_t)(c + 1) * 57600);
            r0 = g[t]; r1 = g[t + 256];
            if (t < 64) r2 = g[t + 512];
        }
        float* dst = gdst + (size_t)c * 57600;
#pragma unroll
        for (int k = 0; k < 9; ++k) {
            float acc = 0.f;
#pragma unroll
            for (int u = 0; u < 9; ++u) {
                int off = po[k][u];
                int ao = off < 0 ? 0 : off;
                float v = plane[ao];
                acc += (off < 0) ? 0.f : v;
            }
            dst[k * 256 + t] = acc;
        }
        __syncthreads();
        if (c + 1 < CPB) {
            pl4[t] = r0; pl4[t + 256] = r1;
            if (t < 64) pl4[t + 512] = r2;
        }
        __syncthreads();
    }
}

extern "C" void kernel_launch(void* const* d_in, const int* in_sizes, int n_in,
                              void* d_out, int out_size, void* d_ws, size_t ws_size,
                              hipStream_t stream) {
    const float* x1 = (const float*)d_in[0];
    const float* x2 = (const float*)d_in[1];
    const float* x3 = (const float*)d_in[2];
    const float* W  = (const float*)d_in[3];
    float* ws = (float*)d_ws;

    float* qp    = ws + OFF_QP;
    float* kp    = ws + OFF_KP;
    float* nk    = ws + OFF_NK;
    float* invNk = ws + OFF_INVNK;
    float* pval  = ws + OFF_PVAL;
    int*   pidx  = (int*)(ws + OFF_PIDX);
    int*   idx   = (int*)(ws + OFF_IDX);
    float* S     = ws + OFF_S;
    int*   soff  = (int*)(ws + OFF_SOFF);   // aliases S; S is dead by k_soff
    float* out   = (float*)d_out;

    const bool bigS = ws_size >= (size_t)(OFF_S + 2u * (unsigned)SSTRIDE) * 4u;

    // zero-pad borders of qp/kp (contiguous 2M floats)
    hipMemsetAsync(qp, 0, 2000000 * sizeof(float), stream);

    k_qk<<<450, 256, 0, stream>>>(x1, x2, W, qp, kp);
    k_nk<<<(2 * NPAD + 255) / 256, 256, 0, stream>>>(kp, nk);
    k_invnk<<<(2 * NPIX + 255) / 256, 256, 0, stream>>>(nk, invNk);

    if (bigS) {
        k_sgemm3<<<dim3(20, 20, 2), 256, 0, stream>>>(qp, kp, S, SSTRIDE, 0);
        k_argmax<<<dim3(48, 48, 2), 384, 0, stream>>>(S, invNk, pval, pidx, SSTRIDE, 0);
    } else {
        for (int b = 0; b < 2; ++b) {
            k_sgemm3<<<dim3(20, 20, 1), 256, 0, stream>>>(qp, kp, S, 0L, b);
            k_argmax<<<dim3(48, 48, 1), 384, 0, stream>>>(S, invNk, pval, pidx, 0L, b);
        }
    }
    k_argred<<<(2 * NPIX + 255) / 256, 256, 0, stream>>>(pval, pidx, idx);
    k_soff<<<(2 * NPIX + 255) / 256, 256, 0, stream>>>(idx, soff);
    k_out2<<<dim3(50, 16), 256, 0, stream>>>(x3, soff, out);
}